// Round 2
// baseline (226.821 us; speedup 1.0000x reference)
//
#include <hip/hip_runtime.h>
#include <hip/hip_bf16.h>

#define V 50000
#define E 256
#define RADIUS 180
#define TAA_W (2 * RADIUS + 1)   // 361
#define BATCH 2048
#define CTX_L 200
#define NOPT 10

// Kernel 1: per-row log-sum-exp of taa_matrix (f32). Bias dropped: softmax is
// invariant to a per-row constant. One wave per row, 6 elems per lane.
__global__ __launch_bounds__(256) void taa_lse_kernel(
    const float* __restrict__ taa, float* __restrict__ lse)
{
    int lane = threadIdx.x & 63;
    int row  = blockIdx.x * 4 + (threadIdx.x >> 6);
    if (row >= V) return;
    const float* p = taa + (size_t)row * TAA_W;
    float x[6];
#pragma unroll
    for (int k = 0; k < 6; ++k) {
        int i = lane + 64 * k;
        x[k] = (i < TAA_W) ? p[i] : -INFINITY;
    }
    float m = x[0];
#pragma unroll
    for (int k = 1; k < 6; ++k) m = fmaxf(m, x[k]);
    for (int off = 32; off > 0; off >>= 1) m = fmaxf(m, __shfl_xor(m, off, 64));
    float s = 0.f;
#pragma unroll
    for (int k = 0; k < 6; ++k) s += __expf(x[k] - m);
    for (int off = 32; off > 0; off >>= 1) s += __shfl_xor(s, off, 64);
    if (lane == 0) lse[row] = m + __logf(s);
}

// Kernel 2: one block (256 thr = 4 waves) per batch row b.
//  A) threads 0..199: w[l] = mask * exp(taa[ev][td] - lse[ev])  -> LDS
//  B) wave ws handles l = ws, ws+4, ...: each lane loads float4 (16B) of the
//     1KB embedding row -> full row per wave per instr; f32 accumulate.
//  C) wave-per-option dot(target_emb_row, hidden) -> f32 scores
__global__ __launch_bounds__(256) void mce_taa_main_kernel(
    const int*   __restrict__ ctx,      // (B, L, 2) int32
    const int*   __restrict__ mt,       // (B, NOPT+1) int32
    const float* __restrict__ ctx_tab,  // (V, E) f32
    const float* __restrict__ tgt_tab,  // (V, E) f32
    const float* __restrict__ taa,      // (V, 361) f32
    const float* __restrict__ lse,      // (V,) f32
    float*       __restrict__ out)      // (B, NOPT) f32
{
    __shared__ int   s_ev[CTX_L];
    __shared__ float s_w[CTX_L];
    __shared__ float s_part[4 * E];
    __shared__ float s_hid[E];

    const int b   = blockIdx.x;
    const int tid = threadIdx.x;
    const int tgt_time = mt[b * (NOPT + 1) + NOPT];

    if (tid < CTX_L) {
        int2 ct = ((const int2*)ctx)[b * CTX_L + tid];
        int ev = ct.x, t = ct.y;
        int mask = (ev == -1) ? 0 : 1;
        ev = mask ? ev : 0;
        if (ev < 0) ev += V;   // jax negative-index wrap safety
        int td = t - tgt_time + RADIUS;
        td = min(max(td, 0), 2 * RADIUS);
        float x = taa[(size_t)ev * TAA_W + td];
        float w = mask ? __expf(x - lse[ev]) : 0.f;
        s_ev[tid] = ev;
        s_w[tid]  = w;
    }
    __syncthreads();

    const int ws   = tid >> 6;   // wave slot 0..3
    const int lane = tid & 63;

    float a0 = 0.f, a1 = 0.f, a2 = 0.f, a3 = 0.f;
    const float4* tab4 = (const float4*)ctx_tab;   // 64 float4 per row
#pragma unroll 5
    for (int l0 = 0; l0 < CTX_L; l0 += 4) {
        int    l  = l0 + ws;
        int    ev = s_ev[l];
        float  w  = s_w[l];
        float4 u  = tab4[(size_t)ev * (E / 4) + lane];
        a0 = fmaf(u.x, w, a0);
        a1 = fmaf(u.y, w, a1);
        a2 = fmaf(u.z, w, a2);
        a3 = fmaf(u.w, w, a3);
    }
    {
        float* p = &s_part[ws * E + lane * 4];
        p[0] = a0; p[1] = a1; p[2] = a2; p[3] = a3;
    }
    __syncthreads();
    s_hid[tid] = s_part[tid] + s_part[E + tid] + s_part[2 * E + tid] + s_part[3 * E + tid];
    __syncthreads();

    const float4* ttab4 = (const float4*)tgt_tab;
    for (int n = ws; n < NOPT; n += 4) {
        int tg = mt[b * (NOPT + 1) + n];
        if (tg < 0) tg += V;
        float4 u = ttab4[(size_t)tg * (E / 4) + lane];
        float p = u.x * s_hid[lane * 4 + 0]
                + u.y * s_hid[lane * 4 + 1]
                + u.z * s_hid[lane * 4 + 2]
                + u.w * s_hid[lane * 4 + 3];
        for (int off = 32; off > 0; off >>= 1) p += __shfl_xor(p, off, 64);
        if (lane == 0) out[b * NOPT + n] = p;
    }
}

extern "C" void kernel_launch(void* const* d_in, const int* in_sizes, int n_in,
                              void* d_out, int out_size, void* d_ws, size_t ws_size,
                              hipStream_t stream) {
    const int*   ctx     = (const int*)d_in[0];
    const int*   mt      = (const int*)d_in[1];
    const float* ctx_tab = (const float*)d_in[2];
    const float* tgt_tab = (const float*)d_in[3];
    const float* taa     = (const float*)d_in[4];
    // d_in[5] = taa_bias: per-row constant inside softmax -> mathematically irrelevant
    float* lse = (float*)d_ws;                 // V floats = 200 KB scratch
    float* out = (float*)d_out;

    taa_lse_kernel<<<(V + 3) / 4, 256, 0, stream>>>(taa, lse);
    mce_taa_main_kernel<<<BATCH, 256, 0, stream>>>(ctx, mt, ctx_tab, tgt_tab,
                                                   taa, lse, out);
}